// Round 16
// baseline (157.104 us; speedup 1.0000x reference)
//
#include <hip/hip_runtime.h>

#define D        128
#define THREADS  512                  // prep / fallback block size
#define B_ROWS   131072

// ---- main (streamed-weights) kernel geometry: 256 threads, 16-row tiles ----
#define THREADS_WS 256
#define MT_WS      16
#define NT_WS      (B_ROWS / MT_WS)   // 8192 tiles
#define GRID_WS    1024               // 4 blocks/CU
#define NTPER_WS   (NT_WS / GRID_WS)  // 8 iterations, exact

#define GRID_FB  512

typedef __bf16  bf16x8  __attribute__((ext_vector_type(8)));
typedef float   f32x4   __attribute__((ext_vector_type(4)));

#define LOG2E 1.4426950408889634f
// ws layout: [0, 64KB)    wd frags (4096 x 16B): idx = slot*512 + kb*64 + lane, slot=0..7
//            [64KB,128KB) wg frags (gamma-folded, bf16-rounded)
//            [128KB,130KB) params f32x4[128]: {sigmoid(log_step), b_in+bias,
//                                              b_gate+beta.Wg^T, colsum(bf16(gamma*Wg))}
#define WS_FRAGS      4096
#define WS_PARAMS_OFF (2 * WS_FRAGS)                    // in 16B units
#define WS_NEEDED     (2 * WS_FRAGS * 16 + 128 * 16)

__device__ __forceinline__ float fexp2(float x) { return __builtin_amdgcn_exp2f(x); }
__device__ __forceinline__ float frcp(float x)  { return __builtin_amdgcn_rcpf(x); }

// tanh(x) = 1 - 2/(e^{2x}+1); inf-safe (e->inf => rcp->0 => 1; e->0 => -1)
__device__ __forceinline__ float fast_tanh(float x) {
    float e = fexp2(x * (2.f * LOG2E));
    return 1.f - 2.f * frcp(e + 1.f);
}
__device__ __forceinline__ float fast_sigmoid(float x) {
    return frcp(1.f + fexp2(-LOG2E * x));
}

// ---------------- pre-kernel: fold + repack weights into B-frag order ----------------
__global__ __launch_bounds__(THREADS)
void prep(const float* __restrict__ w_in,   const float* __restrict__ b_in,
          const float* __restrict__ w_rec,  const float* __restrict__ w_gate,
          const float* __restrict__ b_gate, const float* __restrict__ bias,
          const float* __restrict__ log_step,
          const float* __restrict__ gamma,  const float* __restrict__ beta,
          bf16x8* __restrict__ ws)
{
    const int bid = blockIdx.x, tid = threadIdx.x;
    if (bid < 8) {
        // one thread per fragment: t = (slot, kb, lane)
        const int t    = bid * THREADS + tid;     // 0..4095
        const int l    = t & 63;
        const int kb   = (t >> 6) & 7;
        const int w    = (t >> 9) & 7;            // col-slot 0..7
        const int hcol = w * 16 + (l & 15);
        const int k    = kb * 32 + ((l >> 4) & 3) * 8;
        bf16x8 fd, fg;
        const float* s1 = (k < 128) ? (w_in + hcol * 128 + k) : (w_rec + hcol * 128 + (k - 128));
        const float* s2 = w_gate + hcol * 256 + k;
        #pragma unroll
        for (int j = 0; j < 8; ++j) {
            fd[j] = (__bf16)s1[j];
            fg[j] = (__bf16)(s2[j] * gamma[k + j]);
        }
        ws[t]            = fd;   // wd
        ws[WS_FRAGS + t] = fg;   // wg (gamma folded)
    } else {
        // params: 4 threads per output column h
        const int h   = tid >> 2;          // 0..127
        const int sub = tid & 3;
        float bacc = 0.f, csum = 0.f;
        const float* wp = w_gate + h * 256 + sub * 64;
        const float* gp = gamma + sub * 64;
        const float* bp = beta  + sub * 64;
        #pragma unroll
        for (int k = 0; k < 64; ++k) {
            const float wv = wp[k];
            bacc += wv * bp[k];
            csum += (float)(__bf16)(wv * gp[k]);   // bitwise-consistent with wg frags
        }
        bacc += __shfl_xor(bacc, 1);
        bacc += __shfl_xor(bacc, 2);
        csum += __shfl_xor(csum, 1);
        csum += __shfl_xor(csum, 2);
        if (sub == 0) {
            f32x4 p;
            p[0] = fast_sigmoid(log_step[h]);
            p[1] = b_in[h] + bias[h];
            p[2] = b_gate[h] + bacc;
            p[3] = csum;
            *((f32x4*)(ws + WS_PARAMS_OFF) + h) = p;
        }
    }
}

// ------- main: 256-thread blocks (4 barrier groups/CU), 16-row tiles, 2 col groups/wave -------
__global__ __launch_bounds__(THREADS_WS, 4)
void liquid_cell_ws(const float* __restrict__ x, const float* __restrict__ st,
                    const bf16x8* __restrict__ ws, float* __restrict__ out)
{
    // 16x128 bf16 half-tiles, XOR-swizzled: elem ^= (row&7)<<3 (16B blocks preserved)
    __shared__ __align__(16) __bf16 XT[MT_WS * 128];   // x
    __shared__ __align__(16) __bf16 TT[MT_WS * 128];   // tanh(state)
    __shared__ __align__(16) __bf16 SS[MT_WS * 128];   // raw state (GEMM2 half + epilogue base)
    __shared__ float2 MUB[MT_WS];                      // per-row {mu*rstd, rstd}

    const int tid  = threadIdx.x;
    const int lane = tid & 63;
    const int wave = tid >> 6;             // 0..3
    const int q    = lane >> 4;
    const int arow = lane & 15;
    const int koff = q * 8;

    // two column groups per wave: slots (wave) and (wave+4)
    const int hcol0 = wave * 16 + arow;
    const int hcol1 = hcol0 + 64;
    const int fb0   = wave * 512 + lane;
    const int fb1   = (wave + 4) * 512 + lane;

    const f32x4 p0 = *((const f32x4*)(ws + WS_PARAMS_OFF) + hcol0);
    const f32x4 p1 = *((const f32x4*)(ws + WS_PARAMS_OFF) + hcol1);

    const bf16x8* WD = ws;
    const bf16x8* WG = ws + WS_FRAGS;

    const int r    = tid >> 4;              // row within tile, 0..15
    const int c0   = (tid & 15) * 8;        // 8-col chunk
    const int sw   = (r & 7) << 3;          // write swizzle (bf16-elem units)
    const int rsw  = (arow & 7) << 3;       // read swizzle (row = arow here)

    #pragma unroll 1
    for (int it = 0; it < NTPER_WS; ++it) {
        const long tile = (long)blockIdx.x + (long)it * GRID_WS;

        // ---- phase A: load + stats + bf16 fragments (1 row/thread) ----
        const float* xp = x  + (tile * MT_WS + r) * D + c0;
        const float* sp = st + (tile * MT_WS + r) * D + c0;
        const f32x4 xa = *(const f32x4*)xp, xb = *(const f32x4*)(xp + 4);
        const f32x4 sa = *(const f32x4*)sp, sb = *(const f32x4*)(sp + 4);

        float sum = 0.f, sq = 0.f;
        #pragma unroll
        for (int j = 0; j < 4; ++j) {
            sum += xa[j] + xb[j] + sa[j] + sb[j];
            sq  += xa[j]*xa[j] + xb[j]*xb[j] + sa[j]*sa[j] + sb[j]*sb[j];
        }
        #pragma unroll
        for (int m = 1; m < 16; m <<= 1) {
            sum += __shfl_xor(sum, m);
            sq  += __shfl_xor(sq,  m);
        }
        const float mu   = sum * (1.f / 256.f);
        const float rstd = __builtin_amdgcn_rsqf(sq * (1.f / 256.f) - mu * mu + 1e-5f);

        bf16x8 fx, ft, fs;
        #pragma unroll
        for (int j = 0; j < 4; ++j) {
            fx[j]     = (__bf16)xa[j];
            fx[j + 4] = (__bf16)xb[j];
            ft[j]     = (__bf16)fast_tanh(sa[j]);
            ft[j + 4] = (__bf16)fast_tanh(sb[j]);
            fs[j]     = (__bf16)sa[j];
            fs[j + 4] = (__bf16)sb[j];
        }

        __syncthreads();   // prior iteration's LDS reads complete
        *(bf16x8*)&XT[(r * 128 + c0) ^ sw] = fx;
        *(bf16x8*)&TT[(r * 128 + c0) ^ sw] = ft;
        *(bf16x8*)&SS[(r * 128 + c0) ^ sw] = fs;
        if ((tid & 15) == 0) MUB[r] = make_float2(mu * rstd, rstd);
        __syncthreads();   // tile + stats visible

        // ---- GEMM2 (both column groups, sequential frag streams) ----
        f32x4 acc2g0 = (f32x4)(0.f), acc2g1 = (f32x4)(0.f);
        {
            bf16x8 fw[8];
            #pragma unroll
            for (int kb = 0; kb < 8; ++kb) fw[kb] = WG[fb0 + kb * 64];
            const int base = arow * 128;
            #pragma unroll
            for (int kb = 0; kb < 4; ++kb) {
                bf16x8 a = *(const bf16x8*)&XT[base + ((kb * 32 + koff) ^ rsw)];
                acc2g0 = __builtin_amdgcn_mfma_f32_16x16x32_bf16(a, fw[kb], acc2g0, 0, 0, 0);
            }
            #pragma unroll
            for (int kb = 4; kb < 8; ++kb) {
                bf16x8 a = *(const bf16x8*)&SS[base + (((kb - 4) * 32 + koff) ^ rsw)];
                acc2g0 = __builtin_amdgcn_mfma_f32_16x16x32_bf16(a, fw[kb], acc2g0, 0, 0, 0);
            }
        }
        {
            bf16x8 fw[8];
            #pragma unroll
            for (int kb = 0; kb < 8; ++kb) fw[kb] = WG[fb1 + kb * 64];
            const int base = arow * 128;
            #pragma unroll
            for (int kb = 0; kb < 4; ++kb) {
                bf16x8 a = *(const bf16x8*)&XT[base + ((kb * 32 + koff) ^ rsw)];
                acc2g1 = __builtin_amdgcn_mfma_f32_16x16x32_bf16(a, fw[kb], acc2g1, 0, 0, 0);
            }
            #pragma unroll
            for (int kb = 4; kb < 8; ++kb) {
                bf16x8 a = *(const bf16x8*)&SS[base + (((kb - 4) * 32 + koff) ^ rsw)];
                acc2g1 = __builtin_amdgcn_mfma_f32_16x16x32_bf16(a, fw[kb], acc2g1, 0, 0, 0);
            }
        }

        // ---- gate for both groups (acc2 dies here) ----
        float gate0[4], gate1[4];
        #pragma unroll
        for (int rg = 0; rg < 4; ++rg) {
            const float2 mr = MUB[q * 4 + rg];
            gate0[rg] = fast_sigmoid(mr.y * acc2g0[rg] - mr.x * p0[3] + p0[2]);
            gate1[rg] = fast_sigmoid(mr.y * acc2g1[rg] - mr.x * p1[3] + p1[2]);
        }

        // ---- GEMM1 (both column groups) ----
        f32x4 acc1g0 = (f32x4)(0.f), acc1g1 = (f32x4)(0.f);
        {
            bf16x8 fv[8];
            #pragma unroll
            for (int kb = 0; kb < 8; ++kb) fv[kb] = WD[fb0 + kb * 64];
            const int base = arow * 128;
            #pragma unroll
            for (int kb = 0; kb < 4; ++kb) {
                bf16x8 a = *(const bf16x8*)&XT[base + ((kb * 32 + koff) ^ rsw)];
                acc1g0 = __builtin_amdgcn_mfma_f32_16x16x32_bf16(a, fv[kb], acc1g0, 0, 0, 0);
            }
            #pragma unroll
            for (int kb = 4; kb < 8; ++kb) {
                bf16x8 a = *(const bf16x8*)&TT[base + (((kb - 4) * 32 + koff) ^ rsw)];
                acc1g0 = __builtin_amdgcn_mfma_f32_16x16x32_bf16(a, fv[kb], acc1g0, 0, 0, 0);
            }
        }
        {
            bf16x8 fv[8];
            #pragma unroll
            for (int kb = 0; kb < 8; ++kb) fv[kb] = WD[fb1 + kb * 64];
            const int base = arow * 128;
            #pragma unroll
            for (int kb = 0; kb < 4; ++kb) {
                bf16x8 a = *(const bf16x8*)&XT[base + ((kb * 32 + koff) ^ rsw)];
                acc1g1 = __builtin_amdgcn_mfma_f32_16x16x32_bf16(a, fv[kb], acc1g1, 0, 0, 0);
            }
            #pragma unroll
            for (int kb = 4; kb < 8; ++kb) {
                bf16x8 a = *(const bf16x8*)&TT[base + (((kb - 4) * 32 + koff) ^ rsw)];
                acc1g1 = __builtin_amdgcn_mfma_f32_16x16x32_bf16(a, fv[kb], acc1g1, 0, 0, 0);
            }
        }

        // ---- epilogue: 8 outputs/thread (2 groups x 4 rows) ----
        const long obase = tile * MT_WS;
        #pragma unroll
        for (int rg = 0; rg < 4; ++rg) {
            const int row = q * 4 + rg;
            const float s0     = (float)SS[(row * 128 + hcol0) ^ ((row & 7) << 3)];
            const float t0     = fast_tanh(acc1g0[rg] + p0[1]);
            const float b0     = fminf(p0[0] * gate0[rg], 1.f);
            out[(obase + row) * D + hcol0] = s0 + b0 * (t0 - s0);

            const float s1     = (float)SS[(row * 128 + hcol1) ^ ((row & 7) << 3)];
            const float t1     = fast_tanh(acc1g1[rg] + p1[1]);
            const float b1     = fminf(p1[0] * gate1[rg], 1.f);
            out[(obase + row) * D + hcol1] = s1 + b1 * (t1 - s1);
        }
    }
}

// ---------------- fallback: exact round-3 kernel (known-good) ----------------
__global__ __launch_bounds__(THREADS, 4)
void liquid_cell_fb(const float* __restrict__ x,      const float* __restrict__ st,
                    const float* __restrict__ w_in,   const float* __restrict__ b_in,
                    const float* __restrict__ w_rec,  const float* __restrict__ w_gate,
                    const float* __restrict__ b_gate, const float* __restrict__ bias,
                    const float* __restrict__ log_step,
                    const float* __restrict__ gamma,  const float* __restrict__ beta,
                    float* __restrict__ out)
{
    __shared__ __align__(16) __bf16 A1[32 * 256];
    __shared__ __align__(16) __bf16 A2[32 * 256];
    __shared__ __align__(16) float  SBUF[32 * 128];

    const int tid  = threadIdx.x;
    const int lane = tid & 63;
    const int wave = tid >> 6;
    const int q    = lane >> 4;
    const int arow = lane & 15;
    const int hcol = wave * 16 + arow;
    const int koff = q * 8;

    const float stepv = fast_sigmoid(log_step[hcol]);
    const float bd    = b_in[hcol] + bias[hcol];
    float       bg    = b_gate[hcol];

    bf16x8 wd[8], wg[8];
    float betaAcc = 0.f;
    #pragma unroll
    for (int kb = 0; kb < 8; ++kb) {
        const int k = kb * 32 + koff;
        const float* s1 = (k < 128) ? (w_in  + hcol * 128 + k)
                                    : (w_rec + hcol * 128 + (k - 128));
        const float* s2 = w_gate + hcol * 256 + k;
        #pragma unroll
        for (int j = 0; j < 8; ++j) {
            wd[kb][j] = (__bf16)s1[j];
            const float wv = s2[j];
            wg[kb][j] = (__bf16)(wv * gamma[k + j]);
            betaAcc  += wv * beta[k + j];
        }
    }
    betaAcc += __shfl_xor(betaAcc, 16);
    betaAcc += __shfl_xor(betaAcc, 32);
    bg += betaAcc;

    const int r    = tid >> 4;
    const int c0   = (tid & 15) * 8;
    const int sw   = (r & 7) << 3;
    const int swf  = (r & 7) << 2;
    const int rsw  = (arow & 7) << 3;

    for (int tile = blockIdx.x; tile < (B_ROWS / 32); tile += GRID_FB) {
        const float* xp = x  + ((long)tile * 32 + r) * D + c0;
        const float* sp = st + ((long)tile * 32 + r) * D + c0;
        const f32x4 xa = *(const f32x4*)xp, xb = *(const f32x4*)(xp + 4);
        const f32x4 sa = *(const f32x4*)sp, sb = *(const f32x4*)(sp + 4);

        float sum = 0.f, sq = 0.f;
        #pragma unroll
        for (int j = 0; j < 4; ++j) {
            sum += xa[j] + xb[j] + sa[j] + sb[j];
            sq  += xa[j]*xa[j] + xb[j]*xb[j] + sa[j]*sa[j] + sb[j]*sb[j];
        }
        #pragma unroll
        for (int m = 1; m < 16; m <<= 1) {
            sum += __shfl_xor(sum, m);
            sq  += __shfl_xor(sq,  m);
        }
        const float mu   = sum * (1.f / 256.f);
        const float rstd = __builtin_amdgcn_rsqf(sq * (1.f / 256.f) - mu * mu + 1e-5f);
        const float nmur = -mu * rstd;

        bf16x8 a1x, a1s, a2x, a2s;
        #pragma unroll
        for (int j = 0; j < 4; ++j) {
            a1x[j]     = (__bf16)xa[j];
            a1x[j + 4] = (__bf16)xb[j];
            a1s[j]     = (__bf16)fast_tanh(sa[j]);
            a1s[j + 4] = (__bf16)fast_tanh(sb[j]);
            a2x[j]     = (__bf16)(xa[j] * rstd + nmur);
            a2x[j + 4] = (__bf16)(xb[j] * rstd + nmur);
            a2s[j]     = (__bf16)(sa[j] * rstd + nmur);
            a2s[j + 4] = (__bf16)(sb[j] * rstd + nmur);
        }

        __syncthreads();
        *(bf16x8*)&A1[(r * 256 +       c0) ^ sw] = a1x;
        *(bf16x8*)&A1[(r * 256 + 128 + c0) ^ sw] = a1s;
        *(bf16x8*)&A2[(r * 256 +       c0) ^ sw] = a2x;
        *(bf16x8*)&A2[(r * 256 + 128 + c0) ^ sw] = a2s;
        *(f32x4*)&SBUF[(r * 128 + c0)     ^ swf] = sa;
        *(f32x4*)&SBUF[(r * 128 + c0 + 4) ^ swf] = sb;
        __syncthreads();

        f32x4 acc1[2], acc2[2];
        #pragma unroll
        for (int ms = 0; ms < 2; ++ms) { acc1[ms] = (f32x4)(0.f); acc2[ms] = (f32x4)(0.f); }

        #pragma unroll
        for (int ms = 0; ms < 2; ++ms) {
            const int base = (ms * 16 + arow) * 256;
            #pragma unroll
            for (int kb = 0; kb < 8; ++kb) {
                bf16x8 a = *(const bf16x8*)&A1[base + ((kb * 32 + koff) ^ rsw)];
                acc1[ms] = __builtin_amdgcn_mfma_f32_16x16x32_bf16(a, wd[kb], acc1[ms], 0, 0, 0);
            }
            #pragma unroll
            for (int kb = 0; kb < 8; ++kb) {
                bf16x8 a = *(const bf16x8*)&A2[base + ((kb * 32 + koff) ^ rsw)];
                acc2[ms] = __builtin_amdgcn_mfma_f32_16x16x32_bf16(a, wg[kb], acc2[ms], 0, 0, 0);
            }
        }

        const long obase = (long)tile * 32;
        #pragma unroll
        for (int ms = 0; ms < 2; ++ms) {
            #pragma unroll
            for (int rg = 0; rg < 4; ++rg) {
                const int row = ms * 16 + q * 4 + rg;
                const float s      = SBUF[(row * 128 + hcol) ^ ((row & 7) << 2)];
                const float target = fast_tanh(acc1[ms][rg] + bd);
                const float gate   = fast_sigmoid(acc2[ms][rg] + bg);
                const float blend  = fminf(stepv * gate, 1.f);
                out[(obase + row) * D + hcol] = s + blend * (target - s);
            }
        }
    }
}

extern "C" void kernel_launch(void* const* d_in, const int* in_sizes, int n_in,
                              void* d_out, int out_size, void* d_ws, size_t ws_size,
                              hipStream_t stream) {
    const float* x        = (const float*)d_in[0];
    const float* st       = (const float*)d_in[1];
    const float* w_in     = (const float*)d_in[2];
    const float* b_in     = (const float*)d_in[3];
    const float* w_rec    = (const float*)d_in[4];
    const float* w_gate   = (const float*)d_in[5];
    const float* b_gate   = (const float*)d_in[6];
    const float* bias     = (const float*)d_in[7];
    const float* log_step = (const float*)d_in[8];
    const float* gamma    = (const float*)d_in[9];
    const float* beta     = (const float*)d_in[10];
    float* out = (float*)d_out;

    if (ws_size >= (size_t)WS_NEEDED) {
        bf16x8* ws = (bf16x8*)d_ws;
        hipLaunchKernelGGL(prep, dim3(9), dim3(THREADS), 0, stream,
                           w_in, b_in, w_rec, w_gate, b_gate, bias,
                           log_step, gamma, beta, ws);
        hipLaunchKernelGGL(liquid_cell_ws, dim3(GRID_WS), dim3(THREADS_WS), 0, stream,
                           x, st, ws, out);
    } else {
        hipLaunchKernelGGL(liquid_cell_fb, dim3(GRID_FB), dim3(THREADS), 0, stream,
                           x, st, w_in, b_in, w_rec, w_gate, b_gate, bias,
                           log_step, gamma, beta, out);
    }
}

// Round 17
// 57.265 us; speedup vs baseline: 2.7434x; 2.7434x over previous
//
#include <hip/hip_runtime.h>

#define D        128
#define M_TILE   32
#define THREADS  512
#define B_ROWS   131072
#define NTILES   (B_ROWS / M_TILE)   // 4096
#define GRID     512

typedef __bf16  bf16x8  __attribute__((ext_vector_type(8)));
typedef float   f32x4   __attribute__((ext_vector_type(4)));

#define LOG2E 1.4426950408889634f
// ws layout: [0, 64KB)    wd frags (4096 x 16B): idx = wave*512 + kb*64 + lane
//            [64KB,128KB) wg frags (gamma-folded, bf16-rounded)
//            [128KB,130KB) params f32x4[128]: {sigmoid(log_step), b_in+bias,
//                                              b_gate+beta.Wg^T, colsum(bf16(gamma*Wg))}
#define WS_FRAGS      4096
#define WS_PARAMS_OFF (2 * WS_FRAGS)                    // in 16B units
#define WS_NEEDED     (2 * WS_FRAGS * 16 + 128 * 16)

__device__ __forceinline__ float fexp2(float x) { return __builtin_amdgcn_exp2f(x); }
__device__ __forceinline__ float frcp(float x)  { return __builtin_amdgcn_rcpf(x); }

// tanh(x) = 1 - 2/(e^{2x}+1); inf-safe (e->inf => rcp->0 => 1; e->0 => -1)
__device__ __forceinline__ float fast_tanh(float x) {
    float e = fexp2(x * (2.f * LOG2E));
    return 1.f - 2.f * frcp(e + 1.f);
}
__device__ __forceinline__ float fast_sigmoid(float x) {
    return frcp(1.f + fexp2(-LOG2E * x));
}

// ---------------- pre-kernel: fold + repack weights into B-frag order ----------------
__global__ __launch_bounds__(THREADS)
void prep(const float* __restrict__ w_in,   const float* __restrict__ b_in,
          const float* __restrict__ w_rec,  const float* __restrict__ w_gate,
          const float* __restrict__ b_gate, const float* __restrict__ bias,
          const float* __restrict__ log_step,
          const float* __restrict__ gamma,  const float* __restrict__ beta,
          bf16x8* __restrict__ ws)
{
    const int bid = blockIdx.x, tid = threadIdx.x;
    if (bid < 8) {
        // one thread per fragment: t = (wave, kb, lane)
        const int t    = bid * THREADS + tid;     // 0..4095
        const int l    = t & 63;
        const int kb   = (t >> 6) & 7;
        const int w    = (t >> 9) & 7;
        const int hcol = w * 16 + (l & 15);
        const int k    = kb * 32 + ((l >> 4) & 3) * 8;
        bf16x8 fd, fg;
        const float* s1 = (k < 128) ? (w_in + hcol * 128 + k) : (w_rec + hcol * 128 + (k - 128));
        const float* s2 = w_gate + hcol * 256 + k;
        #pragma unroll
        for (int j = 0; j < 8; ++j) {
            fd[j] = (__bf16)s1[j];
            fg[j] = (__bf16)(s2[j] * gamma[k + j]);
        }
        ws[t]            = fd;   // wd
        ws[WS_FRAGS + t] = fg;   // wg (gamma folded)
    } else {
        // params: 4 threads per output column h
        const int h   = tid >> 2;          // 0..127
        const int sub = tid & 3;
        float bacc = 0.f, csum = 0.f;
        const float* wp = w_gate + h * 256 + sub * 64;
        const float* gp = gamma + sub * 64;
        const float* bp = beta  + sub * 64;
        #pragma unroll
        for (int k = 0; k < 64; ++k) {
            const float wv = wp[k];
            bacc += wv * bp[k];
            csum += (float)(__bf16)(wv * gp[k]);   // bitwise-consistent with wg frags
        }
        bacc += __shfl_xor(bacc, 1);
        bacc += __shfl_xor(bacc, 2);
        csum += __shfl_xor(csum, 1);
        csum += __shfl_xor(csum, 2);
        if (sub == 0) {
            f32x4 p;
            p[0] = fast_sigmoid(log_step[h]);
            p[1] = b_in[h] + bias[h];
            p[2] = b_gate[h] + bacc;
            p[3] = csum;
            *((f32x4*)(ws + WS_PARAMS_OFF) + h) = p;
        }
    }
}

// ------- main kernel: round-12 skeleton, fused dual-GEMM (shared XT reads, 4 MFMA chains) -------
__global__ __launch_bounds__(THREADS, 4)
void liquid_cell_ws(const float* __restrict__ x, const float* __restrict__ st,
                    const bf16x8* __restrict__ ws, float* __restrict__ out)
{
    // 32x128 bf16 half-tiles, XOR-swizzled: elem ^= (row&7)<<3 (16B blocks preserved)
    __shared__ __align__(16) __bf16 XT[M_TILE * 128];   // x
    __shared__ __align__(16) __bf16 TT[M_TILE * 128];   // tanh(state)
    __shared__ __align__(16) __bf16 SS[M_TILE * 128];   // raw state (GEMM2 half + epilogue base)
    __shared__ float2 MUB[M_TILE];                      // per-row {mu*rstd, rstd}

    const int tid  = threadIdx.x;
    const int lane = tid & 63;
    const int wave = tid >> 6;
    const int q    = lane >> 4;
    const int arow = lane & 15;
    const int hcol = wave * 16 + arow;
    const int koff = q * 8;
    const int fbase = wave * 512 + lane;   // frag index: wave*8*64 + lane

    const f32x4 pp = *((const f32x4*)(ws + WS_PARAMS_OFF) + hcol);
    const float stepv = pp[0], bd = pp[1], bg = pp[2], colsum = pp[3];

    const bf16x8* WD = ws;
    const bf16x8* WG = ws + WS_FRAGS;

    const int r    = tid >> 4;              // row within tile, 0..31
    const int c0   = (tid & 15) * 8;        // 8-col chunk
    const int sw   = (r & 7) << 3;          // write swizzle (bf16-elem units)
    const int rsw  = (arow & 7) << 3;       // read swizzle ((ms*16+arow)&7 == arow&7)

    for (int tile = blockIdx.x; tile < NTILES; tile += GRID) {
        // ---- phase A: load + stats + bf16 fragments (no LN applied to the tile) ----
        const float* xp = x  + ((long)tile * M_TILE + r) * D + c0;
        const float* sp = st + ((long)tile * M_TILE + r) * D + c0;
        const f32x4 xa = *(const f32x4*)xp, xb = *(const f32x4*)(xp + 4);
        const f32x4 sa = *(const f32x4*)sp, sb = *(const f32x4*)(sp + 4);

        float sum = 0.f, sq = 0.f;
        #pragma unroll
        for (int j = 0; j < 4; ++j) {
            sum += xa[j] + xb[j] + sa[j] + sb[j];
            sq  += xa[j]*xa[j] + xb[j]*xb[j] + sa[j]*sa[j] + sb[j]*sb[j];
        }
        #pragma unroll
        for (int m = 1; m < 16; m <<= 1) {
            sum += __shfl_xor(sum, m);
            sq  += __shfl_xor(sq,  m);
        }
        const float mu   = sum * (1.f / 256.f);
        const float rstd = __builtin_amdgcn_rsqf(sq * (1.f / 256.f) - mu * mu + 1e-5f);

        bf16x8 fx, ft, fs;
        #pragma unroll
        for (int j = 0; j < 4; ++j) {
            fx[j]     = (__bf16)xa[j];
            fx[j + 4] = (__bf16)xb[j];
            ft[j]     = (__bf16)fast_tanh(sa[j]);
            ft[j + 4] = (__bf16)fast_tanh(sb[j]);
            fs[j]     = (__bf16)sa[j];
            fs[j + 4] = (__bf16)sb[j];
        }

        __syncthreads();   // prior iteration's LDS reads complete
        *(bf16x8*)&XT[(r * 128 + c0) ^ sw] = fx;
        *(bf16x8*)&TT[(r * 128 + c0) ^ sw] = ft;
        *(bf16x8*)&SS[(r * 128 + c0) ^ sw] = fs;
        if ((tid & 15) == 0) MUB[r] = make_float2(mu * rstd, rstd);
        __syncthreads();   // tile + stats visible

        // ---- stream BOTH weight sets (64 regs transient; round-3-proven footprint) ----
        bf16x8 fw[8], fv[8];
        #pragma unroll
        for (int kb = 0; kb < 8; ++kb) {
            fw[kb] = WG[fbase + kb * 64];
            fv[kb] = WD[fbase + kb * 64];
        }

        // ---- fused GEMMs: each XT frag read once, feeds both; 4 independent chains ----
        f32x4 acc2[2], acc1[2];
        acc2[0] = (f32x4)(0.f); acc2[1] = (f32x4)(0.f);
        acc1[0] = (f32x4)(0.f); acc1[1] = (f32x4)(0.f);
        #pragma unroll
        for (int ms = 0; ms < 2; ++ms) {
            const int base = (ms * 16 + arow) * 128;
            #pragma unroll
            for (int kb = 0; kb < 4; ++kb) {
                bf16x8 a = *(const bf16x8*)&XT[base + ((kb * 32 + koff) ^ rsw)];
                acc2[ms] = __builtin_amdgcn_mfma_f32_16x16x32_bf16(a, fw[kb], acc2[ms], 0, 0, 0);
                acc1[ms] = __builtin_amdgcn_mfma_f32_16x16x32_bf16(a, fv[kb], acc1[ms], 0, 0, 0);
            }
            #pragma unroll
            for (int kb = 0; kb < 4; ++kb) {
                bf16x8 s_ = *(const bf16x8*)&SS[base + ((kb * 32 + koff) ^ rsw)];
                acc2[ms] = __builtin_amdgcn_mfma_f32_16x16x32_bf16(s_, fw[kb + 4], acc2[ms], 0, 0, 0);
                bf16x8 t_ = *(const bf16x8*)&TT[base + ((kb * 32 + koff) ^ rsw)];
                acc1[ms] = __builtin_amdgcn_mfma_f32_16x16x32_bf16(t_, fv[kb + 4], acc1[ms], 0, 0, 0);
            }
        }

        // ---- gate + epilogue ----
        const long obase = (long)tile * M_TILE;
        #pragma unroll
        for (int ms = 0; ms < 2; ++ms) {
            #pragma unroll
            for (int rg = 0; rg < 4; ++rg) {
                const int row = ms * 16 + q * 4 + rg;
                const float2 mr = MUB[row];
                const float gate   = fast_sigmoid(mr.y * acc2[ms][rg] - mr.x * colsum + bg);
                const float s      = (float)SS[(row * 128 + hcol) ^ ((row & 7) << 3)];
                const float target = fast_tanh(acc1[ms][rg] + bd);
                const float blend  = fminf(stepv * gate, 1.f);
                out[(obase + row) * D + hcol] = s + blend * (target - s);
            }
        }
    }
}

// ---------------- fallback: exact round-3 kernel (known-good) ----------------
__global__ __launch_bounds__(THREADS, 4)
void liquid_cell_fb(const float* __restrict__ x,      const float* __restrict__ st,
                    const float* __restrict__ w_in,   const float* __restrict__ b_in,
                    const float* __restrict__ w_rec,  const float* __restrict__ w_gate,
                    const float* __restrict__ b_gate, const float* __restrict__ bias,
                    const float* __restrict__ log_step,
                    const float* __restrict__ gamma,  const float* __restrict__ beta,
                    float* __restrict__ out)
{
    __shared__ __align__(16) __bf16 A1[32 * 256];
    __shared__ __align__(16) __bf16 A2[32 * 256];
    __shared__ __align__(16) float  SBUF[32 * 128];

    const int tid  = threadIdx.x;
    const int lane = tid & 63;
    const int wave = tid >> 6;
    const int q    = lane >> 4;
    const int arow = lane & 15;
    const int hcol = wave * 16 + arow;
    const int koff = q * 8;

    const float stepv = fast_sigmoid(log_step[hcol]);
    const float bd    = b_in[hcol] + bias[hcol];
    float       bg    = b_gate[hcol];

    bf16x8 wd[8], wg[8];
    float betaAcc = 0.f;
    #pragma unroll
    for (int kb = 0; kb < 8; ++kb) {
        const int k = kb * 32 + koff;
        const float* s1 = (k < 128) ? (w_in  + hcol * 128 + k)
                                    : (w_rec + hcol * 128 + (k - 128));
        const float* s2 = w_gate + hcol * 256 + k;
        #pragma unroll
        for (int j = 0; j < 8; ++j) {
            wd[kb][j] = (__bf16)s1[j];
            const float wv = s2[j];
            wg[kb][j] = (__bf16)(wv * gamma[k + j]);
            betaAcc  += wv * beta[k + j];
        }
    }
    betaAcc += __shfl_xor(betaAcc, 16);
    betaAcc += __shfl_xor(betaAcc, 32);
    bg += betaAcc;

    const int r    = tid >> 4;
    const int c0   = (tid & 15) * 8;
    const int sw   = (r & 7) << 3;
    const int swf  = (r & 7) << 2;
    const int rsw  = (arow & 7) << 3;

    for (int tile = blockIdx.x; tile < (B_ROWS / 32); tile += GRID) {
        const float* xp = x  + ((long)tile * 32 + r) * D + c0;
        const float* sp = st + ((long)tile * 32 + r) * D + c0;
        const f32x4 xa = *(const f32x4*)xp, xb = *(const f32x4*)(xp + 4);
        const f32x4 sa = *(const f32x4*)sp, sb = *(const f32x4*)(sp + 4);

        float sum = 0.f, sq = 0.f;
        #pragma unroll
        for (int j = 0; j < 4; ++j) {
            sum += xa[j] + xb[j] + sa[j] + sb[j];
            sq  += xa[j]*xa[j] + xb[j]*xb[j] + sa[j]*sa[j] + sb[j]*sb[j];
        }
        #pragma unroll
        for (int m = 1; m < 16; m <<= 1) {
            sum += __shfl_xor(sum, m);
            sq  += __shfl_xor(sq,  m);
        }
        const float mu   = sum * (1.f / 256.f);
        const float rstd = __builtin_amdgcn_rsqf(sq * (1.f / 256.f) - mu * mu + 1e-5f);
        const float nmur = -mu * rstd;

        bf16x8 a1x, a1s, a2x, a2s;
        #pragma unroll
        for (int j = 0; j < 4; ++j) {
            a1x[j]     = (__bf16)xa[j];
            a1x[j + 4] = (__bf16)xb[j];
            a1s[j]     = (__bf16)fast_tanh(sa[j]);
            a1s[j + 4] = (__bf16)fast_tanh(sb[j]);
            a2x[j]     = (__bf16)(xa[j] * rstd + nmur);
            a2x[j + 4] = (__bf16)(xb[j] * rstd + nmur);
            a2s[j]     = (__bf16)(sa[j] * rstd + nmur);
            a2s[j + 4] = (__bf16)(sb[j] * rstd + nmur);
        }

        __syncthreads();
        *(bf16x8*)&A1[(r * 256 +       c0) ^ sw] = a1x;
        *(bf16x8*)&A1[(r * 256 + 128 + c0) ^ sw] = a1s;
        *(bf16x8*)&A2[(r * 256 +       c0) ^ sw] = a2x;
        *(bf16x8*)&A2[(r * 256 + 128 + c0) ^ sw] = a2s;
        *(f32x4*)&SBUF[(r * 128 + c0)     ^ swf] = sa;
        *(f32x4*)&SBUF[(r * 128 + c0 + 4) ^ swf] = sb;
        __syncthreads();

        f32x4 acc1[2], acc2[2];
        #pragma unroll
        for (int ms = 0; ms < 2; ++ms) { acc1[ms] = (f32x4)(0.f); acc2[ms] = (f32x4)(0.f); }

        #pragma unroll
        for (int ms = 0; ms < 2; ++ms) {
            const int base = (ms * 16 + arow) * 256;
            #pragma unroll
            for (int kb = 0; kb < 8; ++kb) {
                bf16x8 a = *(const bf16x8*)&A1[base + ((kb * 32 + koff) ^ rsw)];
                acc1[ms] = __builtin_amdgcn_mfma_f32_16x16x32_bf16(a, wd[kb], acc1[ms], 0, 0, 0);
            }
            #pragma unroll
            for (int kb = 0; kb < 8; ++kb) {
                bf16x8 a = *(const bf16x8*)&A2[base + ((kb * 32 + koff) ^ rsw)];
                acc2[ms] = __builtin_amdgcn_mfma_f32_16x16x32_bf16(a, wg[kb], acc2[ms], 0, 0, 0);
            }
        }

        const long obase = (long)tile * 32;
        #pragma unroll
        for (int ms = 0; ms < 2; ++ms) {
            #pragma unroll
            for (int rg = 0; rg < 4; ++rg) {
                const int row = ms * 16 + q * 4 + rg;
                const float s      = SBUF[(row * 128 + hcol) ^ ((row & 7) << 2)];
                const float target = fast_tanh(acc1[ms][rg] + bd);
                const float gate   = fast_sigmoid(acc2[ms][rg] + bg);
                const float blend  = fminf(stepv * gate, 1.f);
                out[(obase + row) * D + hcol] = s + blend * (target - s);
            }
        }
    }
}

extern "C" void kernel_launch(void* const* d_in, const int* in_sizes, int n_in,
                              void* d_out, int out_size, void* d_ws, size_t ws_size,
                              hipStream_t stream) {
    const float* x        = (const float*)d_in[0];
    const float* st       = (const float*)d_in[1];
    const float* w_in     = (const float*)d_in[2];
    const float* b_in     = (const float*)d_in[3];
    const float* w_rec    = (const float*)d_in[4];
    const float* w_gate   = (const float*)d_in[5];
    const float* b_gate   = (const float*)d_in[6];
    const float* bias     = (const float*)d_in[7];
    const float* log_step = (const float*)d_in[8];
    const float* gamma    = (const float*)d_in[9];
    const float* beta     = (const float*)d_in[10];
    float* out = (float*)d_out;

    if (ws_size >= (size_t)WS_NEEDED) {
        bf16x8* ws = (bf16x8*)d_ws;
        hipLaunchKernelGGL(prep, dim3(9), dim3(THREADS), 0, stream,
                           w_in, b_in, w_rec, w_gate, b_gate, bias,
                           log_step, gamma, beta, ws);
        hipLaunchKernelGGL(liquid_cell_ws, dim3(GRID), dim3(THREADS), 0, stream,
                           x, st, ws, out);
    } else {
        hipLaunchKernelGGL(liquid_cell_fb, dim3(GRID), dim3(THREADS), 0, stream,
                           x, st, w_in, b_in, w_rec, w_gate, b_gate, bias,
                           log_step, gamma, beta, out);
    }
}